// Round 1
// baseline (567.605 us; speedup 1.0000x reference)
//
#include <hip/hip_runtime.h>
#include <hip/hip_bf16.h>

#define NN 50000
#define NE 1200000
#define H 64

// ---------------------------------------------------------------------------
// k0: fold small weights.
//   We2[2][64] = We @ Wm1_e            (Wm1 rows 128..191)
//   bp[64]     = be @ Wm1_e + bm1
//   Wma[64][64]= Wm2 @ Wu1_agg         (Wu1 rows 64..127)
//   bma[64]    = bm2 @ Wu1_agg
// ---------------------------------------------------------------------------
__global__ __launch_bounds__(256) void k0_prep(
    const float* __restrict__ We, const float* __restrict__ be,
    const float* __restrict__ Wm1, const float* __restrict__ bm1,
    const float* __restrict__ Wm2, const float* __restrict__ bm2,
    const float* __restrict__ Wu1,
    float* __restrict__ We2, float* __restrict__ bp,
    float* __restrict__ Wma, float* __restrict__ bma)
{
    const int tid = threadIdx.x;
    const int j = tid & (H - 1);
    const int q = tid >> 6;   // 0..3
    if (q == 0) {
        float s0 = 0.f, s1 = 0.f, sb = 0.f;
        for (int k = 0; k < H; ++k) {
            const float w = Wm1[(2 * H + k) * H + j];
            s0 = fmaf(We[k], w, s0);
            s1 = fmaf(We[H + k], w, s1);
            sb = fmaf(be[k], w, sb);
        }
        We2[j]     = s0;
        We2[H + j] = s1;
        bp[j]      = sb + bm1[j];
        float sm = 0.f;
        for (int l = 0; l < H; ++l)
            sm = fmaf(bm2[l], Wu1[(H + l) * H + j], sm);
        bma[j] = sm;
    }
    // Wma rows split across the 4 sub-waves
    for (int k = q * (H / 4); k < (q + 1) * (H / 4); ++k) {
        float s = 0.f;
        for (int l = 0; l < H; ++l)
            s = fmaf(Wm2[k * H + l], Wu1[(H + l) * H + j], s);
        Wma[k * H + j] = s;
    }
}

// ---------------------------------------------------------------------------
// k1: per-node. h = relu(x@Wn1+bn1)@Wn2+bn2 ; A = h@Wm1_dst ; B = h@Wm1_src ;
//     HU = h@Wu1_h.  One wave per node; weight matrices staged in LDS
//     (Wu1_h read through L1 to stay under 64 KB static LDS).
// ---------------------------------------------------------------------------
__global__ __launch_bounds__(256) void k1_node(
    const float* __restrict__ x,
    const float* __restrict__ Wn1, const float* __restrict__ bn1,
    const float* __restrict__ Wn2, const float* __restrict__ bn2,
    const float* __restrict__ Wm1, const float* __restrict__ Wu1,
    float* __restrict__ A, float* __restrict__ B, float* __restrict__ HU)
{
    __shared__ float sWn2[H * H];
    __shared__ float sW1d[H * H];
    __shared__ float sW1s[H * H];
    __shared__ float sh1[4][H];
    __shared__ float sh[4][H];
    const int tid = threadIdx.x;
    for (int i = tid; i < H * H; i += 256) {
        sWn2[i] = Wn2[i];
        sW1d[i] = Wm1[i];             // rows 0..63  (dst part)
        sW1s[i] = Wm1[H * H + i];     // rows 64..127 (src part)
    }
    __syncthreads();
    const int w = tid >> 6, j = tid & 63;
    float wn1k[5];
#pragma unroll
    for (int k = 0; k < 5; ++k) wn1k[k] = Wn1[k * H + j];
    const float b1 = bn1[j], b2 = bn2[j];
    const int stride = gridDim.x * 4;
    for (int n = blockIdx.x * 4 + w; n < NN; n += stride) {
        float h1 = b1;
#pragma unroll
        for (int k = 0; k < 5; ++k) h1 = fmaf(x[n * 5 + k], wn1k[k], h1);
        h1 = fmaxf(h1, 0.f);
        sh1[w][j] = h1;
        __builtin_amdgcn_wave_barrier();
        float hv = b2;
#pragma unroll 16
        for (int k = 0; k < H; ++k) hv = fmaf(sh1[w][k], sWn2[k * H + j], hv);
        sh[w][j] = hv;
        __builtin_amdgcn_wave_barrier();
        float a = 0.f, bb = 0.f, hu = 0.f;
#pragma unroll 8
        for (int k = 0; k < H; ++k) {
            const float hk = sh[w][k];
            a  = fmaf(hk, sW1d[k * H + j], a);
            bb = fmaf(hk, sW1s[k * H + j], bb);
            hu = fmaf(hk, Wu1[k * H + j], hu);   // L1-resident (16 KB)
        }
        A[n * H + j]  = a;
        B[n * H + j]  = bb;
        HU[n * H + j] = hu;
        __builtin_amdgcn_wave_barrier();
    }
}

// ---------------------------------------------------------------------------
// k3: per-edge (one wave per edge).
//   z = A[dst] + B[src] + ea0*We2[0] + ea1*We2[1] + bp ; r = relu(z)
//   R[dst] += r (atomic, skip zero lanes) ; cnt[dst] += 1
// ---------------------------------------------------------------------------
__global__ __launch_bounds__(256) void k3_edge(
    const float* __restrict__ ea,
    const int* __restrict__ eidx,
    const float* __restrict__ A, const float* __restrict__ B,
    const float* __restrict__ We2, const float* __restrict__ bp,
    float* __restrict__ R, float* __restrict__ cnt)
{
    const int j = threadIdx.x & 63;
    const int wave_id = (blockIdx.x * blockDim.x + threadIdx.x) >> 6;
    const int nwaves = (gridDim.x * blockDim.x) >> 6;
    const float w0 = We2[j], w1 = We2[H + j], b = bp[j];
    const int per = (NE + nwaves - 1) / nwaves;
    const int e0 = wave_id * per;
    const int e1 = (e0 + per < NE) ? (e0 + per) : NE;
    for (int e = e0; e < e1; ++e) {
        const int src = eidx[e];
        const int dst = eidx[NE + e];
        const float2 a01 = *(const float2*)(ea + 2 * e);
        float z = A[dst * H + j] + B[src * H + j] + b;
        z = fmaf(a01.x, w0, z);
        z = fmaf(a01.y, w1, z);
        z = fmaxf(z, 0.f);
        if (z > 0.f) unsafeAtomicAdd(&R[dst * H + j], z);
        if (j == 0)  unsafeAtomicAdd(&cnt[dst], 1.0f);
    }
}

// ---------------------------------------------------------------------------
// k4: per-node epilogue.
//   s = R[n]@Wma ; z = HU[n] + (s + cnt*bma)/max(cnt,1) + bu1
//   out = relu(z)@Wu2 + bu2
// ---------------------------------------------------------------------------
__global__ __launch_bounds__(256) void k4_final(
    const float* __restrict__ R, const float* __restrict__ cnt,
    const float* __restrict__ HU,
    const float* __restrict__ Wma, const float* __restrict__ bma,
    const float* __restrict__ bu1,
    const float* __restrict__ Wu2, const float* __restrict__ bu2,
    float* __restrict__ out)
{
    __shared__ float sWma[H * H];
    __shared__ float sWu2[H * H];
    __shared__ float sr[4][H];
    __shared__ float st[4][H];
    const int tid = threadIdx.x;
    for (int i = tid; i < H * H; i += 256) {
        sWma[i] = Wma[i];
        sWu2[i] = Wu2[i];
    }
    __syncthreads();
    const int w = tid >> 6, j = tid & 63;
    const float bmaj = bma[j], bu1j = bu1[j], bu2j = bu2[j];
    const int stride = gridDim.x * 4;
    for (int n = blockIdx.x * 4 + w; n < NN; n += stride) {
        sr[w][j] = R[n * H + j];
        __builtin_amdgcn_wave_barrier();
        float s = 0.f;
#pragma unroll 16
        for (int k = 0; k < H; ++k) s = fmaf(sr[w][k], sWma[k * H + j], s);
        const float c = cnt[n];
        const float cc = fmaxf(c, 1.0f);
        float z = HU[n * H + j] + (s + c * bmaj) / cc + bu1j;
        z = fmaxf(z, 0.f);
        st[w][j] = z;
        __builtin_amdgcn_wave_barrier();
        float o = bu2j;
#pragma unroll 16
        for (int k = 0; k < H; ++k) o = fmaf(st[w][k], sWu2[k * H + j], o);
        out[n * H + j] = o;
        __builtin_amdgcn_wave_barrier();
    }
}

// ---------------------------------------------------------------------------
extern "C" void kernel_launch(void* const* d_in, const int* in_sizes, int n_in,
                              void* d_out, int out_size, void* d_ws, size_t ws_size,
                              hipStream_t stream) {
    (void)in_sizes; (void)n_in; (void)out_size; (void)ws_size;
    const float* x    = (const float*)d_in[0];
    const float* eatt = (const float*)d_in[1];
    const int*   eidx = (const int*)d_in[2];
    const float* Wn1  = (const float*)d_in[3];
    const float* bn1  = (const float*)d_in[4];
    const float* Wn2  = (const float*)d_in[5];
    const float* bn2  = (const float*)d_in[6];
    const float* We   = (const float*)d_in[7];
    const float* be   = (const float*)d_in[8];
    const float* Wm1  = (const float*)d_in[9];
    const float* bm1  = (const float*)d_in[10];
    const float* Wm2  = (const float*)d_in[11];
    const float* bm2  = (const float*)d_in[12];
    const float* Wu1  = (const float*)d_in[13];
    const float* bu1  = (const float*)d_in[14];
    const float* Wu2  = (const float*)d_in[15];
    const float* bu2  = (const float*)d_in[16];
    float* out = (float*)d_out;

    float* ws  = (float*)d_ws;
    float* A   = ws;                      // N*H
    float* B   = A   + (size_t)NN * H;    // N*H
    float* HU  = B   + (size_t)NN * H;    // N*H
    float* R   = HU  + (size_t)NN * H;    // N*H
    float* cnt = R   + (size_t)NN * H;    // N
    float* We2 = cnt + NN;                // 2*H
    float* bp  = We2 + 2 * H;             // H
    float* Wma = bp  + H;                 // H*H
    float* bma = Wma + H * H;             // H

    // zero R and cnt (contiguous)
    hipMemsetAsync(R, 0, ((size_t)NN * H + NN) * sizeof(float), stream);

    k0_prep<<<1, 256, 0, stream>>>(We, be, Wm1, bm1, Wm2, bm2, Wu1,
                                   We2, bp, Wma, bma);
    k1_node<<<1024, 256, 0, stream>>>(x, Wn1, bn1, Wn2, bn2, Wm1, Wu1,
                                      A, B, HU);
    k3_edge<<<2048, 256, 0, stream>>>(eatt, eidx, A, B, We2, bp, R, cnt);
    k4_final<<<1024, 256, 0, stream>>>(R, cnt, HU, Wma, bma, bu1, Wu2, bu2,
                                       out);
}

// Round 2
// 471.376 us; speedup vs baseline: 1.2041x; 1.2041x over previous
//
#include <hip/hip_runtime.h>
#include <hip/hip_bf16.h>

#define NN 50000
#define NE 1200000
#define H 64

// ---------------------------------------------------------------------------
// k0: fold small weights.
//   We2[2][64] = We @ Wm1_e            (Wm1 rows 128..191)
//   bp[64]     = be @ Wm1_e + bm1
//   Wma[64][64]= Wm2 @ Wu1_agg         (Wu1 rows 64..127)
//   bma[64]    = bm2 @ Wu1_agg
// ---------------------------------------------------------------------------
__global__ __launch_bounds__(256) void k0_prep(
    const float* __restrict__ We, const float* __restrict__ be,
    const float* __restrict__ Wm1, const float* __restrict__ bm1,
    const float* __restrict__ Wm2, const float* __restrict__ bm2,
    const float* __restrict__ Wu1,
    float* __restrict__ We2, float* __restrict__ bp,
    float* __restrict__ Wma, float* __restrict__ bma)
{
    const int tid = threadIdx.x;
    const int j = tid & (H - 1);
    const int q = tid >> 6;   // 0..3
    if (q == 0) {
        float s0 = 0.f, s1 = 0.f, sb = 0.f;
        for (int k = 0; k < H; ++k) {
            const float w = Wm1[(2 * H + k) * H + j];
            s0 = fmaf(We[k], w, s0);
            s1 = fmaf(We[H + k], w, s1);
            sb = fmaf(be[k], w, sb);
        }
        We2[j]     = s0;
        We2[H + j] = s1;
        bp[j]      = sb + bm1[j];
        float sm = 0.f;
        for (int l = 0; l < H; ++l)
            sm = fmaf(bm2[l], Wu1[(H + l) * H + j], sm);
        bma[j] = sm;
    }
    for (int k = q * (H / 4); k < (q + 1) * (H / 4); ++k) {
        float s = 0.f;
        for (int l = 0; l < H; ++l)
            s = fmaf(Wm2[k * H + l], Wu1[(H + l) * H + j], s);
        Wma[k * H + j] = s;
    }
}

// ---------------------------------------------------------------------------
// k1: per-node. h = relu(x@Wn1+bn1)@Wn2+bn2 ; A = h@Wm1_dst ; B = h@Wm1_src ;
//     HU = h@Wu1_h.  One wave per node.
// ---------------------------------------------------------------------------
__global__ __launch_bounds__(256) void k1_node(
    const float* __restrict__ x,
    const float* __restrict__ Wn1, const float* __restrict__ bn1,
    const float* __restrict__ Wn2, const float* __restrict__ bn2,
    const float* __restrict__ Wm1, const float* __restrict__ Wu1,
    float* __restrict__ A, float* __restrict__ B, float* __restrict__ HU)
{
    __shared__ float sWn2[H * H];
    __shared__ float sW1d[H * H];
    __shared__ float sW1s[H * H];
    __shared__ float sh1[4][H];
    __shared__ float sh[4][H];
    const int tid = threadIdx.x;
    for (int i = tid; i < H * H; i += 256) {
        sWn2[i] = Wn2[i];
        sW1d[i] = Wm1[i];             // rows 0..63  (dst part)
        sW1s[i] = Wm1[H * H + i];     // rows 64..127 (src part)
    }
    __syncthreads();
    const int w = tid >> 6, j = tid & 63;
    float wn1k[5];
#pragma unroll
    for (int k = 0; k < 5; ++k) wn1k[k] = Wn1[k * H + j];
    const float b1 = bn1[j], b2 = bn2[j];
    const int stride = gridDim.x * 4;
    for (int n = blockIdx.x * 4 + w; n < NN; n += stride) {
        float h1 = b1;
#pragma unroll
        for (int k = 0; k < 5; ++k) h1 = fmaf(x[n * 5 + k], wn1k[k], h1);
        h1 = fmaxf(h1, 0.f);
        sh1[w][j] = h1;
        __builtin_amdgcn_wave_barrier();
        float hv = b2;
#pragma unroll 16
        for (int k = 0; k < H; ++k) hv = fmaf(sh1[w][k], sWn2[k * H + j], hv);
        sh[w][j] = hv;
        __builtin_amdgcn_wave_barrier();
        float a = 0.f, bb = 0.f, hu = 0.f;
#pragma unroll 8
        for (int k = 0; k < H; ++k) {
            const float hk = sh[w][k];
            a  = fmaf(hk, sW1d[k * H + j], a);
            bb = fmaf(hk, sW1s[k * H + j], bb);
            hu = fmaf(hk, Wu1[k * H + j], hu);   // L1-resident (16 KB)
        }
        A[n * H + j]  = a;
        B[n * H + j]  = bb;
        HU[n * H + j] = hu;
        __builtin_amdgcn_wave_barrier();
    }
}

// ---------------------------------------------------------------------------
// k2a: histogram of dst
// ---------------------------------------------------------------------------
__global__ __launch_bounds__(256) void k2a_hist(
    const int* __restrict__ eidx, int* __restrict__ cnt_i)
{
    const int e = blockIdx.x * blockDim.x + threadIdx.x;
    if (e < NE) atomicAdd(&cnt_i[eidx[NE + e]], 1);
}

// ---------------------------------------------------------------------------
// k2b: single-block exclusive scan of cnt_i[NN] -> off[NN+1], copy to cursor
// 1024 threads = 16 waves; shfl-based scan, 3 barriers per 1024-chunk.
// ---------------------------------------------------------------------------
__global__ __launch_bounds__(1024) void k2b_scan(
    const int* __restrict__ cnt_i, int* __restrict__ off, int* __restrict__ cursor)
{
    __shared__ int wsum[16];
    const int tid = threadIdx.x;
    const int lane = tid & 63, wv = tid >> 6;
    int carry = 0;
    for (int base = 0; base < NN; base += 1024) {
        const int i = base + tid;
        const int v = (i < NN) ? cnt_i[i] : 0;
        // inclusive wave scan
        int s = v;
#pragma unroll
        for (int d = 1; d < 64; d <<= 1) {
            int t = __shfl_up(s, (unsigned)d, 64);
            if (lane >= d) s += t;
        }
        if (lane == 63) wsum[wv] = s;
        __syncthreads();
        if (wv == 0) {
            int ws = (lane < 16) ? wsum[lane] : 0;
#pragma unroll
            for (int d = 1; d < 16; d <<= 1) {
                int t = __shfl_up(ws, (unsigned)d, 64);
                if (lane >= d) ws += t;
            }
            if (lane < 16) wsum[lane] = ws;   // inclusive over wave sums
        }
        __syncthreads();
        const int wbase = wv ? wsum[wv - 1] : 0;
        if (i < NN) {
            const int excl = carry + wbase + (s - v);
            off[i]    = excl;
            cursor[i] = excl;
        }
        carry += wsum[15];
        __syncthreads();   // protect wsum before next chunk overwrites
    }
    if (tid == 0) off[NN] = carry;   // == NE
}

// ---------------------------------------------------------------------------
// k2c: scatter edges into dst-sorted order
// ---------------------------------------------------------------------------
__global__ __launch_bounds__(256) void k2c_scatter(
    const int* __restrict__ eidx, const float* __restrict__ ea,
    int* __restrict__ cursor,
    int* __restrict__ srcS, float2* __restrict__ eaS)
{
    const int e = blockIdx.x * blockDim.x + threadIdx.x;
    if (e < NE) {
        const int dst = eidx[NE + e];
        const int pos = atomicAdd(&cursor[dst], 1);
        srcS[pos] = eidx[e];
        eaS[pos]  = ((const float2*)ea)[e];
    }
}

// ---------------------------------------------------------------------------
// k3_agg: one wave per dst node. Walk contiguous edge list, accumulate
// rsum = sum relu(A[n] + B[src] + ea*We2 + bp) in registers (no atomics),
// then fused update MLP:
//   s = rsum@Wma ; z = HU[n] + (s + cnt*bma)/max(cnt,1) + bu1
//   out = relu(z)@Wu2 + bu2
// ---------------------------------------------------------------------------
__global__ __launch_bounds__(256) void k3_agg(
    const int* __restrict__ off, const int* __restrict__ srcS,
    const float2* __restrict__ eaS,
    const float* __restrict__ A, const float* __restrict__ B,
    const float* __restrict__ HU,
    const float* __restrict__ We2, const float* __restrict__ bp,
    const float* __restrict__ Wma, const float* __restrict__ bma,
    const float* __restrict__ bu1,
    const float* __restrict__ Wu2, const float* __restrict__ bu2,
    float* __restrict__ out)
{
    __shared__ float sWma[H * H];
    __shared__ float sWu2[H * H];
    __shared__ float sr[4][H];
    __shared__ float st[4][H];
    const int tid = threadIdx.x;
    for (int i = tid; i < H * H; i += 256) {
        sWma[i] = Wma[i];
        sWu2[i] = Wu2[i];
    }
    __syncthreads();
    const int w = tid >> 6, j = tid & 63;
    const float w0 = We2[j], w1 = We2[H + j], b = bp[j];
    const float bmaj = bma[j], bu1j = bu1[j], bu2j = bu2[j];
    const int stride = gridDim.x * 4;
    for (int n = blockIdx.x * 4 + w; n < NN; n += stride) {
        const int e0 = __builtin_amdgcn_readfirstlane(off[n]);
        const int e1 = __builtin_amdgcn_readfirstlane(off[n + 1]);
        const float a = A[(size_t)n * H + j] + b;   // fold bias once
        float rsum = 0.f;
        int e = e0;
        for (; e + 4 <= e1; e += 4) {
            const int s0 = srcS[e], s1 = srcS[e + 1], s2 = srcS[e + 2], s3 = srcS[e + 3];
            const float2 q0 = eaS[e], q1 = eaS[e + 1], q2 = eaS[e + 2], q3 = eaS[e + 3];
            const float bb0 = B[(size_t)s0 * H + j];
            const float bb1 = B[(size_t)s1 * H + j];
            const float bb2 = B[(size_t)s2 * H + j];
            const float bb3 = B[(size_t)s3 * H + j];
            float z0 = a + bb0; z0 = fmaf(q0.x, w0, z0); z0 = fmaf(q0.y, w1, z0);
            float z1 = a + bb1; z1 = fmaf(q1.x, w0, z1); z1 = fmaf(q1.y, w1, z1);
            float z2 = a + bb2; z2 = fmaf(q2.x, w0, z2); z2 = fmaf(q2.y, w1, z2);
            float z3 = a + bb3; z3 = fmaf(q3.x, w0, z3); z3 = fmaf(q3.y, w1, z3);
            rsum += fmaxf(z0, 0.f) + fmaxf(z1, 0.f) + fmaxf(z2, 0.f) + fmaxf(z3, 0.f);
        }
        for (; e < e1; ++e) {
            const int s0 = srcS[e];
            const float2 q0 = eaS[e];
            float z0 = a + B[(size_t)s0 * H + j];
            z0 = fmaf(q0.x, w0, z0);
            z0 = fmaf(q0.y, w1, z0);
            rsum += fmaxf(z0, 0.f);
        }
        sr[w][j] = rsum;
        __builtin_amdgcn_wave_barrier();
        float s = 0.f;
#pragma unroll 16
        for (int k = 0; k < H; ++k) s = fmaf(sr[w][k], sWma[k * H + j], s);
        const float c = (float)(e1 - e0);
        const float cc = fmaxf(c, 1.0f);
        float z = HU[(size_t)n * H + j] + (s + c * bmaj) / cc + bu1j;
        z = fmaxf(z, 0.f);
        st[w][j] = z;
        __builtin_amdgcn_wave_barrier();
        float o = bu2j;
#pragma unroll 16
        for (int k = 0; k < H; ++k) o = fmaf(st[w][k], sWu2[k * H + j], o);
        out[(size_t)n * H + j] = o;
        __builtin_amdgcn_wave_barrier();
    }
}

// ---------------------------------------------------------------------------
extern "C" void kernel_launch(void* const* d_in, const int* in_sizes, int n_in,
                              void* d_out, int out_size, void* d_ws, size_t ws_size,
                              hipStream_t stream) {
    (void)in_sizes; (void)n_in; (void)out_size; (void)ws_size;
    const float* x    = (const float*)d_in[0];
    const float* eatt = (const float*)d_in[1];
    const int*   eidx = (const int*)d_in[2];
    const float* Wn1  = (const float*)d_in[3];
    const float* bn1  = (const float*)d_in[4];
    const float* Wn2  = (const float*)d_in[5];
    const float* bn2  = (const float*)d_in[6];
    const float* We   = (const float*)d_in[7];
    const float* be   = (const float*)d_in[8];
    const float* Wm1  = (const float*)d_in[9];
    const float* bm1  = (const float*)d_in[10];
    const float* Wm2  = (const float*)d_in[11];
    const float* bm2  = (const float*)d_in[12];
    const float* Wu1  = (const float*)d_in[13];
    const float* bu1  = (const float*)d_in[14];
    const float* Wu2  = (const float*)d_in[15];
    const float* bu2  = (const float*)d_in[16];
    float* out = (float*)d_out;

    float* ws  = (float*)d_ws;
    float* A    = ws;                         // NN*H
    float* B    = A    + (size_t)NN * H;      // NN*H
    float* HU   = B    + (size_t)NN * H;      // NN*H
    float* eaSf = HU   + (size_t)NN * H;      // NE*2 (float2-aligned: offset even)
    int*   srcS = (int*)(eaSf + (size_t)NE * 2);   // NE
    int*   off  = srcS + NE;                  // NN+1
    int*   curs = off  + NN + 1;              // NN
    int*   cnti = curs + NN;                  // NN
    float* We2  = (float*)(cnti + NN);        // 2*H
    float* bp   = We2  + 2 * H;               // H
    float* Wma  = bp   + H;                   // H*H
    float* bma  = Wma  + H * H;               // H

    hipMemsetAsync(cnti, 0, NN * sizeof(int), stream);

    k0_prep<<<1, 256, 0, stream>>>(We, be, Wm1, bm1, Wm2, bm2, Wu1,
                                   We2, bp, Wma, bma);
    k1_node<<<1024, 256, 0, stream>>>(x, Wn1, bn1, Wn2, bn2, Wm1, Wu1,
                                      A, B, HU);
    k2a_hist<<<(NE + 255) / 256, 256, 0, stream>>>(eidx, cnti);
    k2b_scan<<<1, 1024, 0, stream>>>(cnti, off, curs);
    k2c_scatter<<<(NE + 255) / 256, 256, 0, stream>>>(eidx, eatt, curs,
                                                      srcS, (float2*)eaSf);
    k3_agg<<<1024, 256, 0, stream>>>(off, srcS, (float2*)eaSf,
                                     A, B, HU, We2, bp, Wma, bma,
                                     bu1, Wu2, bu2, out);
}

// Round 3
// 426.626 us; speedup vs baseline: 1.3305x; 1.1049x over previous
//
#include <hip/hip_runtime.h>
#include <hip/hip_bf16.h>

#define NN 50000
#define NE 1200000
#define H 64

// ---------------------------------------------------------------------------
// k0: fold small weights.
//   We2[2][64] = We @ Wm1_e ; bp = be@Wm1_e + bm1
//   Wma[64][64]= Wm2 @ Wu1_agg ; bma = bm2 @ Wu1_agg
// ---------------------------------------------------------------------------
__global__ __launch_bounds__(256) void k0_prep(
    const float* __restrict__ We, const float* __restrict__ be,
    const float* __restrict__ Wm1, const float* __restrict__ bm1,
    const float* __restrict__ Wm2, const float* __restrict__ bm2,
    const float* __restrict__ Wu1,
    float* __restrict__ We2, float* __restrict__ bp,
    float* __restrict__ Wma, float* __restrict__ bma)
{
    const int tid = threadIdx.x;
    const int j = tid & (H - 1);
    const int q = tid >> 6;   // 0..3
    if (q == 0) {
        float s0 = 0.f, s1 = 0.f, sb = 0.f;
        for (int k = 0; k < H; ++k) {
            const float w = Wm1[(2 * H + k) * H + j];
            s0 = fmaf(We[k], w, s0);
            s1 = fmaf(We[H + k], w, s1);
            sb = fmaf(be[k], w, sb);
        }
        We2[j]     = s0;
        We2[H + j] = s1;
        bp[j]      = sb + bm1[j];
        float sm = 0.f;
        for (int l = 0; l < H; ++l)
            sm = fmaf(bm2[l], Wu1[(H + l) * H + j], sm);
        bma[j] = sm;
    }
    for (int k = q * (H / 4); k < (q + 1) * (H / 4); ++k) {
        float s = 0.f;
        for (int l = 0; l < H; ++l)
            s = fmaf(Wm2[k * H + l], Wu1[(H + l) * H + j], s);
        Wma[k * H + j] = s;
    }
}

// ---------------------------------------------------------------------------
// k1: per-node. h = relu(x@Wn1+bn1)@Wn2+bn2 ; A = h@Wm1_dst (f32) ;
//     B = h@Wm1_src (bf16) ; HU = h@Wu1_h (f32). One wave per node.
// ---------------------------------------------------------------------------
__global__ __launch_bounds__(256) void k1_node(
    const float* __restrict__ x,
    const float* __restrict__ Wn1, const float* __restrict__ bn1,
    const float* __restrict__ Wn2, const float* __restrict__ bn2,
    const float* __restrict__ Wm1, const float* __restrict__ Wu1,
    float* __restrict__ A, unsigned short* __restrict__ Bb,
    float* __restrict__ HU)
{
    __shared__ float sWn2[H * H];
    __shared__ float sW1d[H * H];
    __shared__ float sW1s[H * H];
    __shared__ float sh1[4][H];
    __shared__ float sh[4][H];
    const int tid = threadIdx.x;
    for (int i = tid; i < H * H; i += 256) {
        sWn2[i] = Wn2[i];
        sW1d[i] = Wm1[i];             // rows 0..63  (dst part)
        sW1s[i] = Wm1[H * H + i];     // rows 64..127 (src part)
    }
    __syncthreads();
    const int w = tid >> 6, j = tid & 63;
    float wn1k[5];
#pragma unroll
    for (int k = 0; k < 5; ++k) wn1k[k] = Wn1[k * H + j];
    const float b1 = bn1[j], b2 = bn2[j];
    const int stride = gridDim.x * 4;
    for (int n = blockIdx.x * 4 + w; n < NN; n += stride) {
        float h1 = b1;
#pragma unroll
        for (int k = 0; k < 5; ++k) h1 = fmaf(x[n * 5 + k], wn1k[k], h1);
        h1 = fmaxf(h1, 0.f);
        sh1[w][j] = h1;
        __builtin_amdgcn_wave_barrier();
        float hv = b2;
#pragma unroll 16
        for (int k = 0; k < H; ++k) hv = fmaf(sh1[w][k], sWn2[k * H + j], hv);
        sh[w][j] = hv;
        __builtin_amdgcn_wave_barrier();
        float a = 0.f, bb = 0.f, hu = 0.f;
#pragma unroll 8
        for (int k = 0; k < H; ++k) {
            const float hk = sh[w][k];
            a  = fmaf(hk, sW1d[k * H + j], a);
            bb = fmaf(hk, sW1s[k * H + j], bb);
            hu = fmaf(hk, Wu1[k * H + j], hu);   // L1-resident (16 KB)
        }
        A[(size_t)n * H + j]  = a;
        __hip_bfloat16 hb = __float2bfloat16(bb);       // RNE
        Bb[(size_t)n * H + j] = *reinterpret_cast<unsigned short*>(&hb);
        HU[(size_t)n * H + j] = hu;
        __builtin_amdgcn_wave_barrier();
    }
}

// ---------------------------------------------------------------------------
// k2a: histogram of dst
// ---------------------------------------------------------------------------
__global__ __launch_bounds__(256) void k2a_hist(
    const int* __restrict__ eidx, int* __restrict__ cnt_i)
{
    const int e = blockIdx.x * blockDim.x + threadIdx.x;
    if (e < NE) atomicAdd(&cnt_i[eidx[NE + e]], 1);
}

// ---------------------------------------------------------------------------
// Hierarchical scan: s1 (per-block local exclusive scan + block sums),
// s2 (1-wave scan of 49 block sums), s3 (add block offsets, write cursor).
// 1024 elements per block, 49 blocks.
// ---------------------------------------------------------------------------
__global__ __launch_bounds__(256) void k2b_scan1(
    const int* __restrict__ cnt_i, int* __restrict__ off, int* __restrict__ bsum)
{
    __shared__ int wsum[4];
    const int tid = threadIdx.x;
    const int lane = tid & 63, wv = tid >> 6;
    const int base = blockIdx.x * 1024 + tid * 4;
    int v0 = (base + 0 < NN) ? cnt_i[base + 0] : 0;
    int v1 = (base + 1 < NN) ? cnt_i[base + 1] : 0;
    int v2 = (base + 2 < NN) ? cnt_i[base + 2] : 0;
    int v3 = (base + 3 < NN) ? cnt_i[base + 3] : 0;
    const int t0 = v0, t1 = t0 + v1, t2 = t1 + v2, t3 = t2 + v3;
    int s = t3;   // inclusive scan of thread sums within wave
#pragma unroll
    for (int d = 1; d < 64; d <<= 1) {
        int t = __shfl_up(s, (unsigned)d, 64);
        if (lane >= d) s += t;
    }
    if (lane == 63) wsum[wv] = s;
    __syncthreads();
    int wbase = 0;
#pragma unroll
    for (int k = 0; k < 4; ++k) wbase += (k < wv) ? wsum[k] : 0;
    const int excl = wbase + (s - t3);   // exclusive at this thread's start
    if (base + 0 < NN) off[base + 0] = excl;
    if (base + 1 < NN) off[base + 1] = excl + t0;
    if (base + 2 < NN) off[base + 2] = excl + t1;
    if (base + 3 < NN) off[base + 3] = excl + t2;
    if (tid == 0) bsum[blockIdx.x] = wsum[0] + wsum[1] + wsum[2] + wsum[3];
}

__global__ __launch_bounds__(64) void k2b_scan2(
    const int* __restrict__ bsum, int* __restrict__ bsumX)
{
    const int lane = threadIdx.x;
    const int v = (lane < 49) ? bsum[lane] : 0;
    int s = v;
#pragma unroll
    for (int d = 1; d < 64; d <<= 1) {
        int t = __shfl_up(s, (unsigned)d, 64);
        if (lane >= d) s += t;
    }
    if (lane < 49) bsumX[lane] = s - v;   // exclusive
}

__global__ __launch_bounds__(256) void k2b_scan3(
    int* __restrict__ off, const int* __restrict__ bsumX, int* __restrict__ cursor)
{
    const int add = bsumX[blockIdx.x];
    const int base = blockIdx.x * 1024 + threadIdx.x * 4;
#pragma unroll
    for (int k = 0; k < 4; ++k) {
        const int i = base + k;
        if (i < NN) {
            const int o = off[i] + add;
            off[i]    = o;
            cursor[i] = o;
        }
    }
    if (blockIdx.x == 0 && threadIdx.x == 0) off[NN] = NE;
}

// ---------------------------------------------------------------------------
// k2c: scatter edges into dst-sorted order, ONE 16B AoS record per edge:
//   rec[pos] = { src, bits(ea.x), bits(ea.y), 0 }
// ---------------------------------------------------------------------------
__global__ __launch_bounds__(256) void k2c_scatter(
    const int* __restrict__ eidx, const float* __restrict__ ea,
    int* __restrict__ cursor, int4* __restrict__ rec)
{
    const int e = blockIdx.x * blockDim.x + threadIdx.x;
    if (e < NE) {
        const int dst = eidx[NE + e];
        const float2 q = ((const float2*)ea)[e];
        const int pos = atomicAdd(&cursor[dst], 1);
        int4 r;
        r.x = eidx[e];
        r.y = __float_as_int(q.x);
        r.z = __float_as_int(q.y);
        r.w = 0;
        rec[pos] = r;
    }
}

// ---------------------------------------------------------------------------
// k3_agg: one wave per dst node. Walk contiguous records, accumulate
// rsum = sum relu(A[n] + B[src] + ea*We2 + bp) in registers, then fused
// update MLP -> out.  B gathered as bf16 (halved gather traffic).
// ---------------------------------------------------------------------------
__global__ __launch_bounds__(256) void k3_agg(
    const int* __restrict__ off, const int4* __restrict__ rec,
    const float* __restrict__ A, const unsigned short* __restrict__ Bb,
    const float* __restrict__ HU,
    const float* __restrict__ We2, const float* __restrict__ bp,
    const float* __restrict__ Wma, const float* __restrict__ bma,
    const float* __restrict__ bu1,
    const float* __restrict__ Wu2, const float* __restrict__ bu2,
    float* __restrict__ out)
{
    __shared__ float sWma[H * H];
    __shared__ float sWu2[H * H];
    __shared__ float sr[4][H];
    __shared__ float st[4][H];
    const int tid = threadIdx.x;
    for (int i = tid; i < H * H; i += 256) {
        sWma[i] = Wma[i];
        sWu2[i] = Wu2[i];
    }
    __syncthreads();
    const int w = tid >> 6, j = tid & 63;
    const float w0 = We2[j], w1 = We2[H + j], b = bp[j];
    const float bmaj = bma[j], bu1j = bu1[j], bu2j = bu2[j];
    const int stride = gridDim.x * 4;
    for (int n = blockIdx.x * 4 + w; n < NN; n += stride) {
        const int e0 = __builtin_amdgcn_readfirstlane(off[n]);
        const int e1 = __builtin_amdgcn_readfirstlane(off[n + 1]);
        const float a = A[(size_t)n * H + j] + b;   // fold bias once
        float rsum = 0.f;
        int e = e0;
        for (; e + 4 <= e1; e += 4) {
            const int4 r0 = rec[e], r1 = rec[e + 1], r2 = rec[e + 2], r3 = rec[e + 3];
            const float bb0 = __uint_as_float((unsigned)Bb[(size_t)r0.x * H + j] << 16);
            const float bb1 = __uint_as_float((unsigned)Bb[(size_t)r1.x * H + j] << 16);
            const float bb2 = __uint_as_float((unsigned)Bb[(size_t)r2.x * H + j] << 16);
            const float bb3 = __uint_as_float((unsigned)Bb[(size_t)r3.x * H + j] << 16);
            float z0 = a + bb0; z0 = fmaf(__int_as_float(r0.y), w0, z0); z0 = fmaf(__int_as_float(r0.z), w1, z0);
            float z1 = a + bb1; z1 = fmaf(__int_as_float(r1.y), w0, z1); z1 = fmaf(__int_as_float(r1.z), w1, z1);
            float z2 = a + bb2; z2 = fmaf(__int_as_float(r2.y), w0, z2); z2 = fmaf(__int_as_float(r2.z), w1, z2);
            float z3 = a + bb3; z3 = fmaf(__int_as_float(r3.y), w0, z3); z3 = fmaf(__int_as_float(r3.z), w1, z3);
            rsum += fmaxf(z0, 0.f) + fmaxf(z1, 0.f) + fmaxf(z2, 0.f) + fmaxf(z3, 0.f);
        }
        for (; e < e1; ++e) {
            const int4 r0 = rec[e];
            const float bb0 = __uint_as_float((unsigned)Bb[(size_t)r0.x * H + j] << 16);
            float z0 = a + bb0;
            z0 = fmaf(__int_as_float(r0.y), w0, z0);
            z0 = fmaf(__int_as_float(r0.z), w1, z0);
            rsum += fmaxf(z0, 0.f);
        }
        sr[w][j] = rsum;
        __builtin_amdgcn_wave_barrier();
        float s = 0.f;
#pragma unroll 16
        for (int k = 0; k < H; ++k) s = fmaf(sr[w][k], sWma[k * H + j], s);
        const float c = (float)(e1 - e0);
        const float cc = fmaxf(c, 1.0f);
        float z = HU[(size_t)n * H + j] + (s + c * bmaj) / cc + bu1j;
        z = fmaxf(z, 0.f);
        st[w][j] = z;
        __builtin_amdgcn_wave_barrier();
        float o = bu2j;
#pragma unroll 16
        for (int k = 0; k < H; ++k) o = fmaf(st[w][k], sWu2[k * H + j], o);
        out[(size_t)n * H + j] = o;
        __builtin_amdgcn_wave_barrier();
    }
}

// ---------------------------------------------------------------------------
extern "C" void kernel_launch(void* const* d_in, const int* in_sizes, int n_in,
                              void* d_out, int out_size, void* d_ws, size_t ws_size,
                              hipStream_t stream) {
    (void)in_sizes; (void)n_in; (void)out_size; (void)ws_size;
    const float* x    = (const float*)d_in[0];
    const float* eatt = (const float*)d_in[1];
    const int*   eidx = (const int*)d_in[2];
    const float* Wn1  = (const float*)d_in[3];
    const float* bn1  = (const float*)d_in[4];
    const float* Wn2  = (const float*)d_in[5];
    const float* bn2  = (const float*)d_in[6];
    const float* We   = (const float*)d_in[7];
    const float* be   = (const float*)d_in[8];
    const float* Wm1  = (const float*)d_in[9];
    const float* bm1  = (const float*)d_in[10];
    const float* Wm2  = (const float*)d_in[11];
    const float* bm2  = (const float*)d_in[12];
    const float* Wu1  = (const float*)d_in[13];
    const float* bu1  = (const float*)d_in[14];
    const float* Wu2  = (const float*)d_in[15];
    const float* bu2  = (const float*)d_in[16];
    float* out = (float*)d_out;

    char* wsb = (char*)d_ws;
    int4*  rec  = (int4*)wsb;                               // NE*16B (16B aligned)
    float* A    = (float*)(wsb + (size_t)NE * 16);          // NN*H f32
    float* HU   = A + (size_t)NN * H;                       // NN*H f32
    unsigned short* Bb = (unsigned short*)(HU + (size_t)NN * H);  // NN*H bf16
    int*   off  = (int*)(Bb + (size_t)NN * H);              // NN+1
    int*   curs = off  + NN + 1;                            // NN
    int*   cnti = curs + NN;                                // NN
    int*   bsum = cnti + NN;                                // 64
    int*   bsumX= bsum + 64;                                // 64
    float* We2  = (float*)(bsumX + 64);                     // 2*H
    float* bp   = We2  + 2 * H;                             // H
    float* Wma  = bp   + H;                                 // H*H
    float* bma  = Wma  + H * H;                             // H

    hipMemsetAsync(cnti, 0, NN * sizeof(int), stream);

    k0_prep<<<1, 256, 0, stream>>>(We, be, Wm1, bm1, Wm2, bm2, Wu1,
                                   We2, bp, Wma, bma);
    k1_node<<<1024, 256, 0, stream>>>(x, Wn1, bn1, Wn2, bn2, Wm1, Wu1,
                                      A, Bb, HU);
    k2a_hist<<<(NE + 255) / 256, 256, 0, stream>>>(eidx, cnti);
    k2b_scan1<<<49, 256, 0, stream>>>(cnti, off, bsum);
    k2b_scan2<<<1, 64, 0, stream>>>(bsum, bsumX);
    k2b_scan3<<<49, 256, 0, stream>>>(off, bsumX, curs);
    k2c_scatter<<<(NE + 255) / 256, 256, 0, stream>>>(eidx, eatt, curs, rec);
    k3_agg<<<1024, 256, 0, stream>>>(off, rec, A, Bb, HU, We2, bp, Wma, bma,
                                     bu1, Wu2, bu2, out);
}